// Round 1
// baseline (258.850 us; speedup 1.0000x reference)
//
#include <hip/hip_runtime.h>
#include <hip/hip_bf16.h>

#define BSZ 4
#define SEQ 2048
#define DIM 1024

typedef __attribute__((ext_vector_type(8))) short bf16x8;
typedef __attribute__((ext_vector_type(4))) float floatx4;

__device__ __forceinline__ unsigned short f2bf(float x) {
  union { float f; unsigned int u; } v; v.f = x;
  unsigned int r = v.u + 0x7fffu + ((v.u >> 16) & 1u);
  return (unsigned short)(r >> 16);
}

template <typename T> __device__ __forceinline__ void store_c(T* p, float v);
template <> __device__ __forceinline__ void store_c<float>(float* p, float v) { *p = v; }
template <> __device__ __forceinline__ void store_c<unsigned short>(unsigned short* p, float v) { *p = f2bf(v); }

// ---------------- cast fp32 -> bf16 (R6-proven) ----------------
__global__ __launch_bounds__(256) void cast_e(const float* __restrict__ in,
                                              unsigned short* __restrict__ out, int n) {
  int i = (blockIdx.x * 256 + threadIdx.x) * 4;
  if (i >= n) return;
  float4 v = *(const float4*)(in + i);
  ushort4 o;
  o.x = f2bf(v.x); o.y = f2bf(v.y); o.z = f2bf(v.z); o.w = f2bf(v.w);
  *(ushort4*)(out + i) = o;
}

// ---------------- transpose + cast weights (R6-proven) ----------------
__global__ __launch_bounds__(256) void transpose_w(const float* __restrict__ Wq,
                                                   const float* __restrict__ Wk,
                                                   const float* __restrict__ Wv,
                                                   unsigned short* __restrict__ WtQK,
                                                   unsigned short* __restrict__ WtV) {
  __shared__ float tile[32][33];
  int z = blockIdx.z;
  const float* W = (z == 0) ? Wq : (z == 1) ? Wk : Wv;
  unsigned short* dst = (z == 2) ? WtV : WtQK;
  int row_off = (z == 1) ? 1024 : 0;
  int n0 = blockIdx.x * 32, k0 = blockIdx.y * 32;
  int tx = threadIdx.x, ty = threadIdx.y;
  for (int r = ty; r < 32; r += 8)
    tile[r][tx] = W[(size_t)(k0 + r) * DIM + n0 + tx];
  __syncthreads();
  for (int r = ty; r < 32; r += 8)
    dst[(size_t)(row_off + n0 + r) * DIM + k0 + tx] = f2bf(tile[tx][r]);
}

// ---------------- NEW: 256x256-tile, BK=32, 4-deep-ring pipelined dual projection ----------------
// 512 threads = 8 waves (2 M x 4 N), per-wave 128x64 output, acc[8][4] f32x4.
// Staging: global_load_lds dwordx4 (linear LDS dest), 4 wave-instrs per K-tile.
// BK=32 => LDS row stride 64 B => ds_read_b128 fragment reads are bank-conflict-free
// (lane bank-group = 16*(lr&1)+4*lq covers all 8 groups with 8 lanes each).
// Pipeline: prefetch 3 tiles ahead into ring of 4; counted s_waitcnt vmcnt(8) at
// end of tile (never 0 in steady state); raw s_barrier (no vmcnt(0) drain).
__device__ __forceinline__ void gload16(const unsigned short* g, unsigned short* l) {
  __builtin_amdgcn_global_load_lds(
      (const __attribute__((address_space(1))) unsigned int*)g,
      (__attribute__((address_space(3))) unsigned int*)l, 16, 0, 0);
}

#define NT_PROJ 32  // K=1024 / BK=32

__global__ __launch_bounds__(512, 2) void proj256(
    const unsigned short* __restrict__ Ebf,
    const unsigned short* __restrict__ WtQK,
    const unsigned short* __restrict__ WtV,
    unsigned short* __restrict__ QKo,
    unsigned short* __restrict__ Vt) {
  const unsigned short *A, *B;
  unsigned short* C;
  int ldc, m0, n0;
  int x = blockIdx.x;
  if (x < 256) {                       // QK = Ebf x WtQK^T : [8192][2048]
    m0 = (x >> 3) * 256; n0 = (x & 7) * 256;
    A = Ebf; B = WtQK; C = QKo; ldc = 2 * DIM;
  } else {                             // Vt = WtV x Ebf^T : [1024][8192]
    x -= 256;
    m0 = (x >> 5) * 256; n0 = (x & 31) * 256;
    A = WtV; B = Ebf; C = Vt; ldc = BSZ * SEQ;
  }

  __shared__ __align__(16) unsigned short sA[4][256][32];  // 64 KiB
  __shared__ __align__(16) unsigned short sB[4][256][32];  // 64 KiB

  const int tid = threadIdx.x;
  const int lane = tid & 63;
  const int wid = tid >> 6;            // 0..7
  const int wm = (wid >> 2) * 128;     // wave row block: 0 / 128
  const int wn = (wid & 3) * 64;       // wave col block: 0/64/128/192
  const int lr = lane & 15, lq = lane >> 4;

  // staging addresses: sweep covers 128 rows x 64 B; thread t -> row t>>2, 16B chunk t&3
  const unsigned short* gA = A + (size_t)(m0 + (tid >> 2)) * DIM + (tid & 3) * 8;
  const unsigned short* gB = B + (size_t)(n0 + (tid >> 2)) * DIM + (tid & 3) * 8;
  unsigned short* lA = &sA[0][16 * wid][0];  // wave-uniform LDS base; HW adds lane*16
  unsigned short* lB = &sB[0][16 * wid][0];
  const size_t swG = (size_t)128 * DIM;      // global row stride for sweep 1

#define STAGE_A(T) do { int rb_ = (T) & 3; \
    gload16(gA + (size_t)(T) * 32,       lA + rb_ * 8192); \
    gload16(gA + (size_t)(T) * 32 + swG, lA + rb_ * 8192 + 4096); } while (0)
#define STAGE_B(T) do { int rb_ = (T) & 3; \
    gload16(gB + (size_t)(T) * 32,       lB + rb_ * 8192); \
    gload16(gB + (size_t)(T) * 32 + swG, lB + rb_ * 8192 + 4096); } while (0)

  floatx4 acc[8][4] = {};

  // prologue: prefetch tiles 0,1,2 (12 loads); wait tile0 (oldest 4) done
  STAGE_A(0); STAGE_B(0);
  STAGE_A(1); STAGE_B(1);
  STAGE_A(2); STAGE_B(2);
  asm volatile("s_waitcnt vmcnt(8)" ::: "memory");
  __builtin_amdgcn_s_barrier();

#pragma unroll 1
  for (int T = 0; T < NT_PROJ; ++T) {
    asm volatile("" ::: "memory");  // pin this tile's ds_reads behind the vmcnt+barrier
    const int rb = T & 3;
    bf16x8 af[4], bfr[4];
    // ---------- phase A: C-rows wm..wm+63 ----------
#pragma unroll
    for (int j = 0; j < 4; ++j) bfr[j] = *(const bf16x8*)&sB[rb][wn + j * 16 + lr][lq * 8];
#pragma unroll
    for (int i = 0; i < 4; ++i) af[i] = *(const bf16x8*)&sA[rb][wm + i * 16 + lr][lq * 8];
    if (T + 3 < NT_PROJ) STAGE_A(T + 3);
    __builtin_amdgcn_s_barrier();
    __builtin_amdgcn_s_setprio(1);
#pragma unroll
    for (int i = 0; i < 4; ++i)
#pragma unroll
      for (int j = 0; j < 4; ++j)
        acc[i][j] = __builtin_amdgcn_mfma_f32_16x16x32_bf16(af[i], bfr[j], acc[i][j], 0, 0, 0);
    __builtin_amdgcn_s_setprio(0);
    __builtin_amdgcn_s_barrier();
    // ---------- phase B: C-rows wm+64..wm+127 ----------
#pragma unroll
    for (int i = 0; i < 4; ++i) af[i] = *(const bf16x8*)&sA[rb][wm + 64 + i * 16 + lr][lq * 8];
    if (T + 3 < NT_PROJ) STAGE_B(T + 3);
    __builtin_amdgcn_s_barrier();
    __builtin_amdgcn_s_setprio(1);
#pragma unroll
    for (int i = 0; i < 4; ++i)
#pragma unroll
      for (int j = 0; j < 4; ++j)
        acc[4 + i][j] = __builtin_amdgcn_mfma_f32_16x16x32_bf16(af[i], bfr[j], acc[4 + i][j], 0, 0, 0);
    __builtin_amdgcn_s_setprio(0);
    // counted wait: next tile's 4 loads (issued 3 tiles ago) must be complete after
    // the barrier. Steady state: 12 outstanding -> allow 8. Drain ladder at the end.
    if (T < NT_PROJ - 3)       { asm volatile("s_waitcnt vmcnt(8)" ::: "memory"); }
    else if (T == NT_PROJ - 3) { asm volatile("s_waitcnt vmcnt(4)" ::: "memory"); }
    else if (T == NT_PROJ - 2) { asm volatile("s_waitcnt vmcnt(0)" ::: "memory"); }
    else                       { asm volatile("" ::: "memory"); }
    __builtin_amdgcn_s_barrier();
  }
#undef STAGE_A
#undef STAGE_B

  // epilogue: C/D layout col=lane&15, row=(lane>>4)*4+reg (verified m89/m91)
#pragma unroll
  for (int i = 0; i < 8; ++i) {
    int rbase = m0 + wm + i * 16 + lq * 4;
#pragma unroll
    for (int j = 0; j < 4; ++j) {
      int col = n0 + wn + j * 16 + lr;
#pragma unroll
      for (int r = 0; r < 4; ++r)
        C[(size_t)(rbase + r) * ldc + col] = f2bf(acc[i][j][r]);
    }
  }
}

// ---------------- scores / PV (R6 core + R7 grid tweaks, integer tri decode) ----------------
// MODE 1: scores -> exp numerator (no max subtraction: |s|<~8 << 88), bf16 store,
//         row partial sums via shfl + atomicAdd. Packed lower-triangle grid (exact int decode).
// MODE 2: PV: Keff = min(K, m0+128), reversed m order; acc /= rowsum.
template <typename OutT, int MODE>
__global__ __launch_bounds__(256) void gemm_nt(
    const unsigned short* __restrict__ A, int lda, long long strideA,
    const unsigned short* __restrict__ B, int ldb, long long strideB,
    OutT* __restrict__ C, int ldc, long long strideC,
    int Kdim, float scale, float* __restrict__ rowsum) {
  int m0, n0;
  if constexpr (MODE == 1) {
    int t = blockIdx.x;           // 0..135 -> (mt, nt), nt <= mt, exact integer decode
    int mt = 0;
    while (((mt + 1) * (mt + 2)) / 2 <= t) mt++;
    int nt = t - (mt * (mt + 1)) / 2;
    m0 = mt * 128; n0 = nt * 128;
  } else {
    m0 = (gridDim.y - 1 - blockIdx.y) * 128;  // longest blocks first
    n0 = blockIdx.x * 128;
  }
  int Keff = (MODE == 2) ? min(Kdim, m0 + 128) : Kdim;
  A += (long long)blockIdx.z * strideA;
  B += (long long)blockIdx.z * strideB;
  C += (long long)blockIdx.z * strideC;
  rowsum += (size_t)blockIdx.z * SEQ;

  __shared__ __align__(16) unsigned short As[128][72];
  __shared__ __align__(16) unsigned short Bs[128][72];

  int tid = threadIdx.x;
  int lane = tid & 63;
  int wid = tid >> 6;
  int wm = (wid >> 1) * 64, wn = (wid & 1) * 64;
  int lr = lane & 15, lq = lane >> 4;
  int row = tid >> 3;
  int kc = (tid & 7) * 8;

  const unsigned short* Ab = A + (size_t)(m0 + row) * lda + kc;
  const unsigned short* Bb = B + (size_t)(n0 + row) * ldb + kc;
  size_t la = (size_t)32 * lda, lb = (size_t)32 * ldb;

  uint4 ra0 = *(const uint4*)(Ab);
  uint4 ra1 = *(const uint4*)(Ab + la);
  uint4 ra2 = *(const uint4*)(Ab + 2 * la);
  uint4 ra3 = *(const uint4*)(Ab + 3 * la);
  uint4 rb0 = *(const uint4*)(Bb);
  uint4 rb1 = *(const uint4*)(Bb + lb);
  uint4 rb2 = *(const uint4*)(Bb + 2 * lb);
  uint4 rb3 = *(const uint4*)(Bb + 3 * lb);

  floatx4 acc[4][4] = {};

  for (int k0 = 0; k0 < Keff; k0 += 64) {
    __syncthreads();
    *(uint4*)&As[row][kc]      = ra0;
    *(uint4*)&As[row + 32][kc] = ra1;
    *(uint4*)&As[row + 64][kc] = ra2;
    *(uint4*)&As[row + 96][kc] = ra3;
    *(uint4*)&Bs[row][kc]      = rb0;
    *(uint4*)&Bs[row + 32][kc] = rb1;
    *(uint4*)&Bs[row + 64][kc] = rb2;
    *(uint4*)&Bs[row + 96][kc] = rb3;
    if (k0 + 64 < Keff) {
      const unsigned short* An = Ab + k0 + 64;
      const unsigned short* Bn = Bb + k0 + 64;
      ra0 = *(const uint4*)(An);
      ra1 = *(const uint4*)(An + la);
      ra2 = *(const uint4*)(An + 2 * la);
      ra3 = *(const uint4*)(An + 3 * la);
      rb0 = *(const uint4*)(Bn);
      rb1 = *(const uint4*)(Bn + lb);
      rb2 = *(const uint4*)(Bn + 2 * lb);
      rb3 = *(const uint4*)(Bn + 3 * lb);
    }
    __syncthreads();
#pragma unroll
    for (int kk = 0; kk < 64; kk += 32) {
      bf16x8 af[4], bfr[4];
      int kl = kk + lq * 8;
#pragma unroll
      for (int i = 0; i < 4; i++) af[i] = *(const bf16x8*)&As[wm + i * 16 + lr][kl];
#pragma unroll
      for (int j = 0; j < 4; j++) bfr[j] = *(const bf16x8*)&Bs[wn + j * 16 + lr][kl];
#pragma unroll
      for (int i = 0; i < 4; i++)
#pragma unroll
        for (int j = 0; j < 4; j++)
          acc[i][j] = __builtin_amdgcn_mfma_f32_16x16x32_bf16(af[i], bfr[j], acc[i][j], 0, 0, 0);
    }
  }

  // C/D layout (verified m89/m91): col = lane&15, row = (lane>>4)*4 + reg
  if constexpr (MODE == 1) {
#pragma unroll
    for (int i = 0; i < 4; i++) {
      int rbase = m0 + wm + i * 16 + lq * 4;
      float s0 = 0.f, s1 = 0.f, s2 = 0.f, s3 = 0.f;
#pragma unroll
      for (int j = 0; j < 4; j++) {
        int col = n0 + wn + j * 16 + lr;
        float e0 = (col <= rbase + 0) ? __expf(acc[i][j][0] * scale) : 0.0f;
        float e1 = (col <= rbase + 1) ? __expf(acc[i][j][1] * scale) : 0.0f;
        float e2 = (col <= rbase + 2) ? __expf(acc[i][j][2] * scale) : 0.0f;
        float e3 = (col <= rbase + 3) ? __expf(acc[i][j][3] * scale) : 0.0f;
        store_c(&C[(size_t)(rbase + 0) * ldc + col], e0);
        store_c(&C[(size_t)(rbase + 1) * ldc + col], e1);
        store_c(&C[(size_t)(rbase + 2) * ldc + col], e2);
        store_c(&C[(size_t)(rbase + 3) * ldc + col], e3);
        s0 += e0; s1 += e1; s2 += e2; s3 += e3;
      }
#pragma unroll
      for (int m = 1; m < 16; m <<= 1) {
        s0 += __shfl_xor(s0, m, 64);
        s1 += __shfl_xor(s1, m, 64);
        s2 += __shfl_xor(s2, m, 64);
        s3 += __shfl_xor(s3, m, 64);
      }
      if (lr == 0) {
        atomicAdd(&rowsum[rbase + 0], s0);
        atomicAdd(&rowsum[rbase + 1], s1);
        atomicAdd(&rowsum[rbase + 2], s2);
        atomicAdd(&rowsum[rbase + 3], s3);
      }
    }
  } else {
#pragma unroll
    for (int i = 0; i < 4; i++) {
      int rbase = m0 + wm + i * 16 + lq * 4;
      float i0 = 1.0f / rowsum[rbase + 0];
      float i1 = 1.0f / rowsum[rbase + 1];
      float i2 = 1.0f / rowsum[rbase + 2];
      float i3 = 1.0f / rowsum[rbase + 3];
#pragma unroll
      for (int j = 0; j < 4; j++) {
        int col = n0 + wn + j * 16 + lr;
        store_c(&C[(size_t)(rbase + 0) * ldc + col], acc[i][j][0] * i0);
        store_c(&C[(size_t)(rbase + 1) * ldc + col], acc[i][j][1] * i1);
        store_c(&C[(size_t)(rbase + 2) * ldc + col], acc[i][j][2] * i2);
        store_c(&C[(size_t)(rbase + 3) * ldc + col], acc[i][j][3] * i3);
      }
    }
  }
}

extern "C" void kernel_launch(void* const* d_in, const int* in_sizes, int n_in,
                              void* d_out, int out_size, void* d_ws, size_t ws_size,
                              hipStream_t stream) {
  const float* E  = (const float*)d_in[0];
  const float* Wq = (const float*)d_in[1];
  const float* Wk = (const float*)d_in[2];
  const float* Wv = (const float*)d_in[3];
  float* out = (float*)d_out;

  char* ws = (char*)d_ws;
  size_t off = 0;
  auto alloc = [&](size_t bytes) {
    void* p = ws + off;
    off += (bytes + 255) & ~(size_t)255;
    return p;
  };
  const size_t M_ALL = (size_t)BSZ * SEQ;
  unsigned short* Ebf  = (unsigned short*)alloc(M_ALL * DIM * 2);
  unsigned short* WtQK = (unsigned short*)alloc((size_t)2 * DIM * DIM * 2);
  unsigned short* WtV  = (unsigned short*)alloc((size_t)DIM * DIM * 2);
  unsigned short* QK   = (unsigned short*)alloc(M_ALL * 2 * DIM * 2);
  unsigned short* Vt   = (unsigned short*)alloc((size_t)DIM * M_ALL * 2);
  unsigned short* ExpS = (unsigned short*)alloc((size_t)BSZ * SEQ * SEQ * 2);
  float*          Rsum = (float*)alloc((size_t)BSZ * SEQ * 4);

  int nE = (int)(M_ALL * DIM);
  cast_e<<<dim3(nE / (256 * 4)), dim3(256), 0, stream>>>(E, Ebf, nE);
  transpose_w<<<dim3(32, 32, 3), dim3(32, 8), 0, stream>>>(Wq, Wk, Wv, WtQK, WtV);
  hipMemsetAsync(Rsum, 0, (size_t)BSZ * SEQ * 4, stream);

  // fused QK + Vt projections: 256 QK-tiles + 128 Vt-tiles, 512 threads, 1 block/CU
  proj256<<<dim3(384), dim3(512), 0, stream>>>(Ebf, WtQK, WtV, QK, Vt);

  // scores -> exp numerators (bf16) + rowsum atomics; packed triangular grid
  gemm_nt<unsigned short, 1><<<dim3(136, 1, BSZ), dim3(256), 0, stream>>>(
      QK, 2 * DIM, (long long)SEQ * 2 * DIM,
      QK + DIM, 2 * DIM, (long long)SEQ * 2 * DIM,
      ExpS, SEQ, (long long)SEQ * SEQ,
      DIM, 0.03125f /* 1/sqrt(1024) */, Rsum);

  // PV: out[q][d] = (sum_k expS[q][k] * Vt[d][k]) / rowsum[q]
  gemm_nt<float, 2><<<dim3(8, 16, BSZ), dim3(256), 0, stream>>>(
      ExpS, SEQ, (long long)SEQ * SEQ,
      Vt, (int)M_ALL, (long long)SEQ,
      out, DIM, (long long)SEQ * DIM,
      SEQ, 1.0f, Rsum);
}

// Round 2
// 243.959 us; speedup vs baseline: 1.0610x; 1.0610x over previous
//
#include <hip/hip_runtime.h>
#include <hip/hip_bf16.h>

#define BSZ 4
#define SEQ 2048
#define DIM 1024

typedef __attribute__((ext_vector_type(8))) short bf16x8;
typedef __attribute__((ext_vector_type(4))) float floatx4;

__device__ __forceinline__ unsigned short f2bf(float x) {
  union { float f; unsigned int u; } v; v.f = x;
  unsigned int r = v.u + 0x7fffu + ((v.u >> 16) & 1u);
  return (unsigned short)(r >> 16);
}

template <typename T> __device__ __forceinline__ void store_c(T* p, float v);
template <> __device__ __forceinline__ void store_c<float>(float* p, float v) { *p = v; }
template <> __device__ __forceinline__ void store_c<unsigned short>(unsigned short* p, float v) { *p = f2bf(v); }

// ---------------- cast fp32 -> bf16 (R6-proven) ----------------
__global__ __launch_bounds__(256) void cast_e(const float* __restrict__ in,
                                              unsigned short* __restrict__ out, int n) {
  int i = (blockIdx.x * 256 + threadIdx.x) * 4;
  if (i >= n) return;
  float4 v = *(const float4*)(in + i);
  ushort4 o;
  o.x = f2bf(v.x); o.y = f2bf(v.y); o.z = f2bf(v.z); o.w = f2bf(v.w);
  *(ushort4*)(out + i) = o;
}

// ---------------- transpose + cast weights (R6-proven) ----------------
__global__ __launch_bounds__(256) void transpose_w(const float* __restrict__ Wq,
                                                   const float* __restrict__ Wk,
                                                   const float* __restrict__ Wv,
                                                   unsigned short* __restrict__ WtQK,
                                                   unsigned short* __restrict__ WtV) {
  __shared__ float tile[32][33];
  int z = blockIdx.z;
  const float* W = (z == 0) ? Wq : (z == 1) ? Wk : Wv;
  unsigned short* dst = (z == 2) ? WtV : WtQK;
  int row_off = (z == 1) ? 1024 : 0;
  int n0 = blockIdx.x * 32, k0 = blockIdx.y * 32;
  int tx = threadIdx.x, ty = threadIdx.y;
  for (int r = ty; r < 32; r += 8)
    tile[r][tx] = W[(size_t)(k0 + r) * DIM + n0 + tx];
  __syncthreads();
  for (int r = ty; r < 32; r += 8)
    dst[(size_t)(row_off + n0 + r) * DIM + k0 + tx] = f2bf(tile[tx][r]);
}

// ---------------- pipelined dual projection, R2: swizzled LDS + packed grid ----------------
// BMt x 256 tile, BK=32, ring of 4 LDS buffers, prefetch 3 tiles ahead, counted vmcnt.
// LDS bank-conflict fix (T2 analog, rule #21 both-sides):
//   global source chunk c_src = (tid&3) ^ ((tid>>3)&3)  [bijective per wave 1KB region]
//   ds_read chunk       c_rd  = lq ^ ((row>>1)&3)
//   -> every consecutive 8-lane subgroup of a ds_read_b128 hits 8 distinct 4-bank groups.
__device__ __forceinline__ void gload16(const unsigned short* g, unsigned short* l) {
  __builtin_amdgcn_global_load_lds(
      (const __attribute__((address_space(1))) unsigned int*)g,
      (__attribute__((address_space(3))) unsigned int*)l, 16, 0, 0);
}

#define NT_PROJ 32  // K=1024 / BK=32

template <int BMt>
__device__ __forceinline__ void proj_core(
    const unsigned short* __restrict__ A,
    const unsigned short* __restrict__ Bm,
    unsigned short* __restrict__ C, int ldc, int m0, int n0,
    unsigned short* sAr, unsigned short* sBr) {
  constexpr int LPA = BMt / 128;      // gload insts per A tile: 2 (BMt=256) or 1 (BMt=128)
  constexpr int LPT = LPA + 2;        // loads per tile (A + 2 for B)
  constexpr int FR  = BMt / 32;       // acc fragment rows per wave (8 or 4)
  constexpr int TA  = BMt * 32;       // shorts per A ring slab
  constexpr int TB  = 256 * 32;       // shorts per B ring slab

  const int tid = threadIdx.x;
  const int lane = tid & 63;
  const int wid = tid >> 6;            // 0..7
  const int wm = (wid >> 2) * (BMt / 2);
  const int wn = (wid & 3) * 64;
  const int lr = lane & 15, lq = lane >> 4;

  // staging source (chunk XOR-swizzled); LDS dest stays linear (gload_lds requirement)
  const int srow = tid >> 2;                         // 0..127
  const int schunk = (tid & 3) ^ ((tid >> 3) & 3);   // swizzled 16B chunk within row
  const unsigned short* gA = A + (size_t)(m0 + srow) * DIM + schunk * 8;
  const unsigned short* gB = Bm + (size_t)(n0 + srow) * DIM + schunk * 8;
  unsigned short* lA = sAr + 16 * 32 * wid;  // wave-uniform base; HW adds lane*16B
  unsigned short* lB = sBr + 16 * 32 * wid;
  const size_t swG = (size_t)128 * DIM;      // global row stride for sweep 1

#define STAGE_A(T) do { int rb_ = (T) & 3; \
    gload16(gA + (size_t)(T) * 32, lA + rb_ * TA); \
    if constexpr (LPA == 2) gload16(gA + (size_t)(T) * 32 + swG, lA + rb_ * TA + 4096); } while (0)
#define STAGE_B(T) do { int rb_ = (T) & 3; \
    gload16(gB + (size_t)(T) * 32,       lB + rb_ * TB); \
    gload16(gB + (size_t)(T) * 32 + swG, lB + rb_ * TB + 4096); } while (0)
  // swizzled fragment reads
#define ARD(rb_, rowv) (*(const bf16x8*)&sAr[(rb_) * TA + (rowv) * 32 + (lq ^ (((rowv) >> 1) & 3)) * 8])
#define BRD(rb_, rowv) (*(const bf16x8*)&sBr[(rb_) * TB + (rowv) * 32 + (lq ^ (((rowv) >> 1) & 3)) * 8])

  floatx4 acc[FR][4] = {};

  // prologue: prefetch tiles 0,1,2; wait until tile 0 landed (<= 2*LPT outstanding)
  STAGE_A(0); STAGE_B(0);
  STAGE_A(1); STAGE_B(1);
  STAGE_A(2); STAGE_B(2);
  if constexpr (LPT == 4) asm volatile("s_waitcnt vmcnt(8)" ::: "memory");
  else                    asm volatile("s_waitcnt vmcnt(6)" ::: "memory");
  __builtin_amdgcn_s_barrier();

#pragma unroll 4
  for (int T = 0; T < NT_PROJ; ++T) {
    const int rb = T & 3;
    bf16x8 af[4], bfr[4];
    // ---------- phase A ----------
#pragma unroll
    for (int j = 0; j < 4; ++j) bfr[j] = BRD(rb, wn + j * 16 + lr);
#pragma unroll
    for (int i = 0; i < 4; ++i) af[i] = ARD(rb, wm + i * 16 + lr);
    if (T + 3 < NT_PROJ) {
      STAGE_A(T + 3);
      if constexpr (BMt == 128) STAGE_B(T + 3);
    }
    __builtin_amdgcn_s_barrier();
    __builtin_amdgcn_s_setprio(1);
#pragma unroll
    for (int i = 0; i < 4; ++i)
#pragma unroll
      for (int j = 0; j < 4; ++j)
        acc[i][j] = __builtin_amdgcn_mfma_f32_16x16x32_bf16(af[i], bfr[j], acc[i][j], 0, 0, 0);
    __builtin_amdgcn_s_setprio(0);
    if constexpr (BMt == 256) {
      // ---------- phase B: rows wm+64..wm+127 ----------
      __builtin_amdgcn_s_barrier();
#pragma unroll
      for (int i = 0; i < 4; ++i) af[i] = ARD(rb, wm + 64 + i * 16 + lr);
      if (T + 3 < NT_PROJ) STAGE_B(T + 3);
      __builtin_amdgcn_s_barrier();
      __builtin_amdgcn_s_setprio(1);
#pragma unroll
      for (int i = 0; i < 4; ++i)
#pragma unroll
        for (int j = 0; j < 4; ++j)
          acc[4 + i][j] = __builtin_amdgcn_mfma_f32_16x16x32_bf16(af[i], bfr[j], acc[4 + i][j], 0, 0, 0);
      __builtin_amdgcn_s_setprio(0);
    }
    // counted vmcnt: ensure tile T+1 has landed; never drain to 0 in steady state
    if (T < NT_PROJ - 3) {
      if constexpr (LPT == 4) asm volatile("s_waitcnt vmcnt(8)" ::: "memory");
      else                    asm volatile("s_waitcnt vmcnt(6)" ::: "memory");
    } else if (T == NT_PROJ - 3) {
      if constexpr (LPT == 4) asm volatile("s_waitcnt vmcnt(4)" ::: "memory");
      else                    asm volatile("s_waitcnt vmcnt(3)" ::: "memory");
    } else if (T == NT_PROJ - 2) {
      asm volatile("s_waitcnt vmcnt(0)" ::: "memory");
    }
    __builtin_amdgcn_s_barrier();
  }
#undef STAGE_A
#undef STAGE_B
#undef ARD
#undef BRD

  // epilogue: C/D layout col=lane&15, row=(lane>>4)*4+reg (verified m89/m91)
#pragma unroll
  for (int i = 0; i < FR; ++i) {
    int rbase = m0 + wm + i * 16 + lq * 4;
#pragma unroll
    for (int j = 0; j < 4; ++j) {
      int col = n0 + wn + j * 16 + lr;
#pragma unroll
      for (int r = 0; r < 4; ++r)
        C[(size_t)(rbase + r) * ldc + col] = f2bf(acc[i][j][r]);
    }
  }
}

__global__ __launch_bounds__(512, 2) void proj256(
    const unsigned short* __restrict__ Ebf,
    const unsigned short* __restrict__ WtQK,
    const unsigned short* __restrict__ WtV,
    unsigned short* __restrict__ QKo,
    unsigned short* __restrict__ Vt) {
  __shared__ __align__(16) unsigned short sA[4 * 256 * 32];  // 64 KiB
  __shared__ __align__(16) unsigned short sB[4 * 256 * 32];  // 64 KiB
  int x = blockIdx.x;
  if (x < 256) {
    // QK = Ebf x WtQK^T : [8192][2048], 256x256 tiles, 32x8 grid
    proj_core<256>(Ebf, WtQK, QKo, 2 * DIM, (x >> 3) * 256, (x & 7) * 256, sA, sB);
  } else {
    // Vt = WtV x Ebf^T : [1024][8192], 128x256 tiles, 8x32 grid (half-work round: perfect fill)
    x -= 256;
    proj_core<128>(WtV, Ebf, Vt, BSZ * SEQ, (x >> 5) * 128, (x & 31) * 256, sA, sB);
  }
}

// ---------------- scores / PV (R6 core + R7 grid tweaks, integer tri decode) ----------------
// MODE 1: scores -> exp numerator (no max subtraction: |s|<~8 << 88), bf16 store,
//         row partial sums via shfl + atomicAdd. Packed lower-triangle grid (exact int decode).
// MODE 2: PV: Keff = min(K, m0+128), reversed m order; acc /= rowsum.
template <typename OutT, int MODE>
__global__ __launch_bounds__(256) void gemm_nt(
    const unsigned short* __restrict__ A, int lda, long long strideA,
    const unsigned short* __restrict__ B, int ldb, long long strideB,
    OutT* __restrict__ C, int ldc, long long strideC,
    int Kdim, float scale, float* __restrict__ rowsum) {
  int m0, n0;
  if constexpr (MODE == 1) {
    int t = blockIdx.x;           // 0..135 -> (mt, nt), nt <= mt, exact integer decode
    int mt = 0;
    while (((mt + 1) * (mt + 2)) / 2 <= t) mt++;
    int nt = t - (mt * (mt + 1)) / 2;
    m0 = mt * 128; n0 = nt * 128;
  } else {
    m0 = (gridDim.y - 1 - blockIdx.y) * 128;  // longest blocks first
    n0 = blockIdx.x * 128;
  }
  int Keff = (MODE == 2) ? min(Kdim, m0 + 128) : Kdim;
  A += (long long)blockIdx.z * strideA;
  B += (long long)blockIdx.z * strideB;
  C += (long long)blockIdx.z * strideC;
  rowsum += (size_t)blockIdx.z * SEQ;

  __shared__ __align__(16) unsigned short As[128][72];
  __shared__ __align__(16) unsigned short Bs[128][72];

  int tid = threadIdx.x;
  int lane = tid & 63;
  int wid = tid >> 6;
  int wm = (wid >> 1) * 64, wn = (wid & 1) * 64;
  int lr = lane & 15, lq = lane >> 4;
  int row = tid >> 3;
  int kc = (tid & 7) * 8;

  const unsigned short* Ab = A + (size_t)(m0 + row) * lda + kc;
  const unsigned short* Bb = B + (size_t)(n0 + row) * ldb + kc;
  size_t la = (size_t)32 * lda, lb = (size_t)32 * ldb;

  uint4 ra0 = *(const uint4*)(Ab);
  uint4 ra1 = *(const uint4*)(Ab + la);
  uint4 ra2 = *(const uint4*)(Ab + 2 * la);
  uint4 ra3 = *(const uint4*)(Ab + 3 * la);
  uint4 rb0 = *(const uint4*)(Bb);
  uint4 rb1 = *(const uint4*)(Bb + lb);
  uint4 rb2 = *(const uint4*)(Bb + 2 * lb);
  uint4 rb3 = *(const uint4*)(Bb + 3 * lb);

  floatx4 acc[4][4] = {};

  for (int k0 = 0; k0 < Keff; k0 += 64) {
    __syncthreads();
    *(uint4*)&As[row][kc]      = ra0;
    *(uint4*)&As[row + 32][kc] = ra1;
    *(uint4*)&As[row + 64][kc] = ra2;
    *(uint4*)&As[row + 96][kc] = ra3;
    *(uint4*)&Bs[row][kc]      = rb0;
    *(uint4*)&Bs[row + 32][kc] = rb1;
    *(uint4*)&Bs[row + 64][kc] = rb2;
    *(uint4*)&Bs[row + 96][kc] = rb3;
    if (k0 + 64 < Keff) {
      const unsigned short* An = Ab + k0 + 64;
      const unsigned short* Bn = Bb + k0 + 64;
      ra0 = *(const uint4*)(An);
      ra1 = *(const uint4*)(An + la);
      ra2 = *(const uint4*)(An + 2 * la);
      ra3 = *(const uint4*)(An + 3 * la);
      rb0 = *(const uint4*)(Bn);
      rb1 = *(const uint4*)(Bn + lb);
      rb2 = *(const uint4*)(Bn + 2 * lb);
      rb3 = *(const uint4*)(Bn + 3 * lb);
    }
    __syncthreads();
#pragma unroll
    for (int kk = 0; kk < 64; kk += 32) {
      bf16x8 af[4], bfr[4];
      int kl = kk + lq * 8;
#pragma unroll
      for (int i = 0; i < 4; i++) af[i] = *(const bf16x8*)&As[wm + i * 16 + lr][kl];
#pragma unroll
      for (int j = 0; j < 4; j++) bfr[j] = *(const bf16x8*)&Bs[wn + j * 16 + lr][kl];
#pragma unroll
      for (int i = 0; i < 4; i++)
#pragma unroll
        for (int j = 0; j < 4; j++)
          acc[i][j] = __builtin_amdgcn_mfma_f32_16x16x32_bf16(af[i], bfr[j], acc[i][j], 0, 0, 0);
    }
  }

  // C/D layout (verified m89/m91): col = lane&15, row = (lane>>4)*4 + reg
  if constexpr (MODE == 1) {
#pragma unroll
    for (int i = 0; i < 4; i++) {
      int rbase = m0 + wm + i * 16 + lq * 4;
      float s0 = 0.f, s1 = 0.f, s2 = 0.f, s3 = 0.f;
#pragma unroll
      for (int j = 0; j < 4; j++) {
        int col = n0 + wn + j * 16 + lr;
        float e0 = (col <= rbase + 0) ? __expf(acc[i][j][0] * scale) : 0.0f;
        float e1 = (col <= rbase + 1) ? __expf(acc[i][j][1] * scale) : 0.0f;
        float e2 = (col <= rbase + 2) ? __expf(acc[i][j][2] * scale) : 0.0f;
        float e3 = (col <= rbase + 3) ? __expf(acc[i][j][3] * scale) : 0.0f;
        store_c(&C[(size_t)(rbase + 0) * ldc + col], e0);
        store_c(&C[(size_t)(rbase + 1) * ldc + col], e1);
        store_c(&C[(size_t)(rbase + 2) * ldc + col], e2);
        store_c(&C[(size_t)(rbase + 3) * ldc + col], e3);
        s0 += e0; s1 += e1; s2 += e2; s3 += e3;
      }
#pragma unroll
      for (int m = 1; m < 16; m <<= 1) {
        s0 += __shfl_xor(s0, m, 64);
        s1 += __shfl_xor(s1, m, 64);
        s2 += __shfl_xor(s2, m, 64);
        s3 += __shfl_xor(s3, m, 64);
      }
      if (lr == 0) {
        atomicAdd(&rowsum[rbase + 0], s0);
        atomicAdd(&rowsum[rbase + 1], s1);
        atomicAdd(&rowsum[rbase + 2], s2);
        atomicAdd(&rowsum[rbase + 3], s3);
      }
    }
  } else {
#pragma unroll
    for (int i = 0; i < 4; i++) {
      int rbase = m0 + wm + i * 16 + lq * 4;
      float i0 = 1.0f / rowsum[rbase + 0];
      float i1 = 1.0f / rowsum[rbase + 1];
      float i2 = 1.0f / rowsum[rbase + 2];
      float i3 = 1.0f / rowsum[rbase + 3];
#pragma unroll
      for (int j = 0; j < 4; j++) {
        int col = n0 + wn + j * 16 + lr;
        store_c(&C[(size_t)(rbase + 0) * ldc + col], acc[i][j][0] * i0);
        store_c(&C[(size_t)(rbase + 1) * ldc + col], acc[i][j][1] * i1);
        store_c(&C[(size_t)(rbase + 2) * ldc + col], acc[i][j][2] * i2);
        store_c(&C[(size_t)(rbase + 3) * ldc + col], acc[i][j][3] * i3);
      }
    }
  }
}

extern "C" void kernel_launch(void* const* d_in, const int* in_sizes, int n_in,
                              void* d_out, int out_size, void* d_ws, size_t ws_size,
                              hipStream_t stream) {
  const float* E  = (const float*)d_in[0];
  const float* Wq = (const float*)d_in[1];
  const float* Wk = (const float*)d_in[2];
  const float* Wv = (const float*)d_in[3];
  float* out = (float*)d_out;

  char* ws = (char*)d_ws;
  size_t off = 0;
  auto alloc = [&](size_t bytes) {
    void* p = ws + off;
    off += (bytes + 255) & ~(size_t)255;
    return p;
  };
  const size_t M_ALL = (size_t)BSZ * SEQ;
  unsigned short* Ebf  = (unsigned short*)alloc(M_ALL * DIM * 2);
  unsigned short* WtQK = (unsigned short*)alloc((size_t)2 * DIM * DIM * 2);
  unsigned short* WtV  = (unsigned short*)alloc((size_t)DIM * DIM * 2);
  unsigned short* QK   = (unsigned short*)alloc(M_ALL * 2 * DIM * 2);
  unsigned short* Vt   = (unsigned short*)alloc((size_t)DIM * M_ALL * 2);
  unsigned short* ExpS = (unsigned short*)alloc((size_t)BSZ * SEQ * SEQ * 2);
  float*          Rsum = (float*)alloc((size_t)BSZ * SEQ * 4);

  int nE = (int)(M_ALL * DIM);
  cast_e<<<dim3(nE / (256 * 4)), dim3(256), 0, stream>>>(E, Ebf, nE);
  transpose_w<<<dim3(32, 32, 3), dim3(32, 8), 0, stream>>>(Wq, Wk, Wv, WtQK, WtV);
  hipMemsetAsync(Rsum, 0, (size_t)BSZ * SEQ * 4, stream);

  // fused QK (256 full-work blocks) + Vt (256 half-work blocks): perfect 2-round packing
  proj256<<<dim3(512), dim3(512), 0, stream>>>(Ebf, WtQK, WtV, QK, Vt);

  // scores -> exp numerators (bf16) + rowsum atomics; packed triangular grid
  gemm_nt<unsigned short, 1><<<dim3(136, 1, BSZ), dim3(256), 0, stream>>>(
      QK, 2 * DIM, (long long)SEQ * 2 * DIM,
      QK + DIM, 2 * DIM, (long long)SEQ * 2 * DIM,
      ExpS, SEQ, (long long)SEQ * SEQ,
      DIM, 0.03125f /* 1/sqrt(1024) */, Rsum);

  // PV: out[q][d] = (sum_k expS[q][k] * Vt[d][k]) / rowsum[q]
  gemm_nt<float, 2><<<dim3(8, 16, BSZ), dim3(256), 0, stream>>>(
      ExpS, SEQ, (long long)SEQ * SEQ,
      Vt, (int)M_ALL, (long long)SEQ,
      out, DIM, (long long)SEQ * DIM,
      SEQ, 1.0f, Rsum);
}

// Round 4
// 243.728 us; speedup vs baseline: 1.0620x; 1.0009x over previous
//
#include <hip/hip_runtime.h>
#include <hip/hip_bf16.h>

#define BSZ 4
#define SEQ 2048
#define DIM 1024

typedef __attribute__((ext_vector_type(8))) short bf16x8;
typedef __attribute__((ext_vector_type(4))) float floatx4;

__device__ __forceinline__ unsigned short f2bf(float x) {
  union { float f; unsigned int u; } v; v.f = x;
  unsigned int r = v.u + 0x7fffu + ((v.u >> 16) & 1u);
  return (unsigned short)(r >> 16);
}

template <typename T> __device__ __forceinline__ void store_c(T* p, float v);
template <> __device__ __forceinline__ void store_c<float>(float* p, float v) { *p = v; }
template <> __device__ __forceinline__ void store_c<unsigned short>(unsigned short* p, float v) { *p = f2bf(v); }

// ---------------- cast fp32 -> bf16 (R6-proven) ----------------
__global__ __launch_bounds__(256) void cast_e(const float* __restrict__ in,
                                              unsigned short* __restrict__ out, int n) {
  int i = (blockIdx.x * 256 + threadIdx.x) * 4;
  if (i >= n) return;
  float4 v = *(const float4*)(in + i);
  ushort4 o;
  o.x = f2bf(v.x); o.y = f2bf(v.y); o.z = f2bf(v.z); o.w = f2bf(v.w);
  *(ushort4*)(out + i) = o;
}

// ---------------- transpose + cast weights (R6-proven) ----------------
__global__ __launch_bounds__(256) void transpose_w(const float* __restrict__ Wq,
                                                   const float* __restrict__ Wk,
                                                   const float* __restrict__ Wv,
                                                   unsigned short* __restrict__ WtQK,
                                                   unsigned short* __restrict__ WtV) {
  __shared__ float tile[32][33];
  int z = blockIdx.z;
  const float* W = (z == 0) ? Wq : (z == 1) ? Wk : Wv;
  unsigned short* dst = (z == 2) ? WtV : WtQK;
  int row_off = (z == 1) ? 1024 : 0;
  int n0 = blockIdx.x * 32, k0 = blockIdx.y * 32;
  int tx = threadIdx.x, ty = threadIdx.y;
  for (int r = ty; r < 32; r += 8)
    tile[r][tx] = W[(size_t)(k0 + r) * DIM + n0 + tx];
  __syncthreads();
  for (int r = ty; r < 32; r += 8)
    dst[(size_t)(row_off + n0 + r) * DIM + k0 + tx] = f2bf(tile[tx][r]);
}

__device__ __forceinline__ void gload16(const unsigned short* g, unsigned short* l) {
  __builtin_amdgcn_global_load_lds(
      (const __attribute__((address_space(1))) unsigned int*)g,
      (__attribute__((address_space(3))) unsigned int*)l, 16, 0, 0);
}

// =====================================================================
// 8-phase 256x256 GEMM core (QK path), R4: RACE-FIXED vmcnt placement.
// Invariant: counted vmcnt ALWAYS precedes the barrier that publishes a
// buffer (per-wave vmcnt certifies own gloads; barrier makes buffer valid
// block-wide). Waits sit AFTER the MFMA cluster so the wave issues MFMAs
// before blocking.
// FIFO ledger (per wave, 2 loads per STG):
//   prologue: B0(4),A0(4),B1(4)=12 out -> vmcnt(4) lands B0+A0 -> BAR.
//   iter: ph0 +A1h0, ph1 +A1h1, ph2 +B0''h0, ph3 +B0''h1 -> 12 out;
//         ph3 vmcnt(4) lands prevB1+A1 -> buf1 valid.
//         ph4 +A0''h0, ph5 +A0''h1, ph6 +B1''h0, ph7 +B1''h1 -> 12 out;
//         ph7 vmcnt(4) lands B0''+A0'' -> next buf0 valid.
//   j=7: no stages; ph3 vmcnt(0) lands all 8; ph7 no wait.
// WAR: every STG target's last ds_read drained by an lgkmcnt(0) >=1
// barrier earlier (checked phase-by-phase).
// Swizzle (both-sides, R2-proven pattern widened to 3 bits): physical
// chunk p of row r holds logical chunk p^(r&7); stage source chunk
// (t&7)^((t>>3)&7); read chunk (kk*4+lq)^(lr&7) -> conflict-free.
// =====================================================================
__device__ __forceinline__ void proj8ph(
    const unsigned short* __restrict__ A,
    const unsigned short* __restrict__ Bm,
    unsigned short* __restrict__ C, int ldc, int m0, int n0,
    unsigned short* sA, unsigned short* sB) {
  const int tid = threadIdx.x;
  const int lane = tid & 63;
  const int wid = tid >> 6;            // 0..7
  const int wm = (wid >> 2) * 128;     // 0 / 128
  const int wn = (wid & 3) * 64;       // 0/64/128/192
  const int lr = lane & 15, lq = lane >> 4;

  // LDS read bases (shorts). half-tile = 8192 shorts (128 rows x 64 k).
  unsigned short* aB = sA + (wm >> 7) * 8192 + lr * 64;
  unsigned short* bB = sB + (wn >> 7) * 8192 + ((wn & 64) + lr) * 64;
  const int sw0 = (lq ^ (lr & 7)) * 8;        // kk=0 swizzled chunk offset
  const int sw1 = ((4 + lq) ^ (lr & 7)) * 8;  // kk=1

  // staging: thread t covers row (t>>3) (+64 for 2nd gload), chunk (t&7)
  const int schunk = (tid & 7) ^ ((tid >> 3) & 7);
  const unsigned short* gA = A + (size_t)(m0 + (tid >> 3)) * DIM + schunk * 8;
  const unsigned short* gB = Bm + (size_t)(n0 + (tid >> 3)) * DIM + schunk * 8;
  unsigned short* lA = sA + wid * 512;  // wave-uniform; HW adds lane*16B
  unsigned short* lB = sB + wid * 512;

#define STG_A(buf, T, half) do { \
    gload16(gA + (size_t)((half) * 128) * DIM + (T) * 64,      lA + (buf) * 16384 + (half) * 8192); \
    gload16(gA + (size_t)((half) * 128 + 64) * DIM + (T) * 64, lA + (buf) * 16384 + (half) * 8192 + 4096); } while (0)
#define STG_B(buf, T, half) do { \
    gload16(gB + (size_t)((half) * 128) * DIM + (T) * 64,      lB + (buf) * 16384 + (half) * 8192); \
    gload16(gB + (size_t)((half) * 128 + 64) * DIM + (T) * 64, lB + (buf) * 16384 + (half) * 8192 + 4096); } while (0)
#define RD_A(buf, qr) do { _Pragma("unroll") for (int i_ = 0; i_ < 4; ++i_) { \
    af[i_][0] = *(const bf16x8*)(aB + (buf) * 16384 + ((qr) * 64 + i_ * 16) * 64 + sw0); \
    af[i_][1] = *(const bf16x8*)(aB + (buf) * 16384 + ((qr) * 64 + i_ * 16) * 64 + sw1); } } while (0)
#define RD_B(buf, qc) do { _Pragma("unroll") for (int j_ = 0; j_ < 2; ++j_) { \
    bq[qc][j_][0] = *(const bf16x8*)(bB + (buf) * 16384 + ((qc) * 32 + j_ * 16) * 64 + sw0); \
    bq[qc][j_][1] = *(const bf16x8*)(bB + (buf) * 16384 + ((qc) * 32 + j_ * 16) * 64 + sw1); } } while (0)
#define MM(qr, qc) do { __builtin_amdgcn_s_setprio(1); \
    _Pragma("unroll") for (int i_ = 0; i_ < 4; ++i_) \
    _Pragma("unroll") for (int jj_ = 0; jj_ < 2; ++jj_) { \
      acc[(qr)*4+i_][(qc)*2+jj_] = __builtin_amdgcn_mfma_f32_16x16x32_bf16(af[i_][0], bq[qc][jj_][0], acc[(qr)*4+i_][(qc)*2+jj_], 0, 0, 0); \
      acc[(qr)*4+i_][(qc)*2+jj_] = __builtin_amdgcn_mfma_f32_16x16x32_bf16(af[i_][1], bq[qc][jj_][1], acc[(qr)*4+i_][(qc)*2+jj_], 0, 0, 0); } \
    __builtin_amdgcn_s_setprio(0); } while (0)
#define BAR __builtin_amdgcn_s_barrier()
#define LGKM0 do { asm volatile("s_waitcnt lgkmcnt(0)" ::: "memory"); __builtin_amdgcn_sched_barrier(0); } while (0)
#define VM4 asm volatile("s_waitcnt vmcnt(4)" ::: "memory")
#define VM0 asm volatile("s_waitcnt vmcnt(0)" ::: "memory")

  floatx4 acc[8][4] = {};
  bf16x8 af[4][2], bq[2][2][2];

  // prologue: B0, A0, B1; certify buf0 (own loads) then publish via barrier
  STG_B(0, 0, 0); STG_B(0, 0, 1);
  STG_A(0, 0, 0); STG_A(0, 0, 1);
  STG_B(1, 1, 0); STG_B(1, 1, 1);
  VM4;   // lands B0+A0 (oldest 8 of 12)
  BAR;   // buf0 now valid block-wide

#pragma unroll 1
  for (int j = 0; j < 8; ++j) {                 // 16 K-tiles, 2 per iter
    const int t0 = 2 * j, t1 = 2 * j + 1;
    const bool st = (j < 7);
    // ---------------- t0 from buf0 (valid: prev ph7 VM+BAR) ----------------
    RD_A(0, 0); RD_B(0, 0);
    STG_A(1, t1, 0);
    BAR; LGKM0; MM(0, 0); BAR;                  // ph0

    RD_B(0, 1);
    STG_A(1, t1, 1);
    BAR; LGKM0; MM(0, 1); BAR;                  // ph1

    RD_A(0, 1);
    if (st) STG_B(0, t0 + 2, 0);                // buf0.B reads drained @ph1
    BAR; LGKM0; MM(1, 0); BAR;                  // ph2

    if (st) STG_B(0, t0 + 2, 1);
    BAR; MM(1, 1);
    if (st) { VM4; } else { VM0; }              // certify buf1 BEFORE publish
    BAR;                                        // ph3: buf1 valid block-wide

    // ---------------- t1 from buf1 ----------------
    RD_A(1, 0); RD_B(1, 0);
    if (st) STG_A(0, t0 + 2, 0);                // buf0.A reads drained @ph2
    BAR; LGKM0; MM(0, 0); BAR;                  // ph4

    RD_B(1, 1);
    if (st) STG_A(0, t0 + 2, 1);
    BAR; LGKM0; MM(0, 1); BAR;                  // ph5

    RD_A(1, 1);
    if (st) STG_B(1, t1 + 2, 0);                // buf1.B reads drained @ph5
    BAR; LGKM0; MM(1, 0); BAR;                  // ph6

    if (st) STG_B(1, t1 + 2, 1);
    BAR; MM(1, 1);
    if (st) { VM4; }                            // certify next buf0 BEFORE publish
    BAR;                                        // ph7: next buf0 valid
  }
#undef STG_A
#undef STG_B
#undef RD_A
#undef RD_B
#undef MM
#undef BAR
#undef LGKM0
#undef VM4
#undef VM0

  // epilogue: C/D layout col=lane&15, row=(lane>>4)*4+reg (verified m89/m91)
#pragma unroll
  for (int i = 0; i < 8; ++i) {
    int rbase = m0 + wm + i * 16 + lq * 4;
#pragma unroll
    for (int jc = 0; jc < 4; ++jc) {
      int col = n0 + wn + jc * 16 + lr;
#pragma unroll
      for (int r = 0; r < 4; ++r)
        C[(size_t)(rbase + r) * ldc + col] = f2bf(acc[i][jc][r]);
    }
  }
}

// ---------------- R2-proven ring-4 core (kept for the Vt half-work round) ----------------
#define NT_PROJ 32  // K=1024 / BK=32

template <int BMt>
__device__ __forceinline__ void proj_core(
    const unsigned short* __restrict__ A,
    const unsigned short* __restrict__ Bm,
    unsigned short* __restrict__ C, int ldc, int m0, int n0,
    unsigned short* sAr, unsigned short* sBr) {
  constexpr int LPA = BMt / 128;
  constexpr int LPT = LPA + 2;
  constexpr int FR  = BMt / 32;
  constexpr int TA  = BMt * 32;
  constexpr int TB  = 256 * 32;

  const int tid = threadIdx.x;
  const int lane = tid & 63;
  const int wid = tid >> 6;
  const int wm = (wid >> 2) * (BMt / 2);
  const int wn = (wid & 3) * 64;
  const int lr = lane & 15, lq = lane >> 4;

  const int srow = tid >> 2;
  const int schunk = (tid & 3) ^ ((tid >> 3) & 3);
  const unsigned short* gA = A + (size_t)(m0 + srow) * DIM + schunk * 8;
  const unsigned short* gB = Bm + (size_t)(n0 + srow) * DIM + schunk * 8;
  unsigned short* lA = sAr + 16 * 32 * wid;
  unsigned short* lB = sBr + 16 * 32 * wid;
  const size_t swG = (size_t)128 * DIM;

#define STAGE_A(T) do { int rb_ = (T) & 3; \
    gload16(gA + (size_t)(T) * 32, lA + rb_ * TA); \
    if constexpr (LPA == 2) gload16(gA + (size_t)(T) * 32 + swG, lA + rb_ * TA + 4096); } while (0)
#define STAGE_B(T) do { int rb_ = (T) & 3; \
    gload16(gB + (size_t)(T) * 32,       lB + rb_ * TB); \
    gload16(gB + (size_t)(T) * 32 + swG, lB + rb_ * TB + 4096); } while (0)
#define ARD(rb_, rowv) (*(const bf16x8*)&sAr[(rb_) * TA + (rowv) * 32 + (lq ^ (((rowv) >> 1) & 3)) * 8])
#define BRD(rb_, rowv) (*(const bf16x8*)&sBr[(rb_) * TB + (rowv) * 32 + (lq ^ (((rowv) >> 1) & 3)) * 8])

  floatx4 acc[FR][4] = {};

  STAGE_A(0); STAGE_B(0);
  STAGE_A(1); STAGE_B(1);
  STAGE_A(2); STAGE_B(2);
  if constexpr (LPT == 4) asm volatile("s_waitcnt vmcnt(8)" ::: "memory");
  else                    asm volatile("s_waitcnt vmcnt(6)" ::: "memory");
  __builtin_amdgcn_s_barrier();

#pragma unroll 4
  for (int T = 0; T < NT_PROJ; ++T) {
    const int rb = T & 3;
    bf16x8 af[4], bfr[4];
#pragma unroll
    for (int j = 0; j < 4; ++j) bfr[j] = BRD(rb, wn + j * 16 + lr);
#pragma unroll
    for (int i = 0; i < 4; ++i) af[i] = ARD(rb, wm + i * 16 + lr);
    if (T + 3 < NT_PROJ) {
      STAGE_A(T + 3);
      if constexpr (BMt == 128) STAGE_B(T + 3);
    }
    __builtin_amdgcn_s_barrier();
    __builtin_amdgcn_s_setprio(1);
#pragma unroll
    for (int i = 0; i < 4; ++i)
#pragma unroll
      for (int j = 0; j < 4; ++j)
        acc[i][j] = __builtin_amdgcn_mfma_f32_16x16x32_bf16(af[i], bfr[j], acc[i][j], 0, 0, 0);
    __builtin_amdgcn_s_setprio(0);
    if constexpr (BMt == 256) {
      __builtin_amdgcn_s_barrier();
#pragma unroll
      for (int i = 0; i < 4; ++i) af[i] = ARD(rb, wm + 64 + i * 16 + lr);
      if (T + 3 < NT_PROJ) STAGE_B(T + 3);
      __builtin_amdgcn_s_barrier();
      __builtin_amdgcn_s_setprio(1);
#pragma unroll
      for (int i = 0; i < 4; ++i)
#pragma unroll
        for (int j = 0; j < 4; ++j)
          acc[4 + i][j] = __builtin_amdgcn_mfma_f32_16x16x32_bf16(af[i], bfr[j], acc[4 + i][j], 0, 0, 0);
      __builtin_amdgcn_s_setprio(0);
    }
    if (T < NT_PROJ - 3) {
      if constexpr (LPT == 4) asm volatile("s_waitcnt vmcnt(8)" ::: "memory");
      else                    asm volatile("s_waitcnt vmcnt(6)" ::: "memory");
    } else if (T == NT_PROJ - 3) {
      if constexpr (LPT == 4) asm volatile("s_waitcnt vmcnt(4)" ::: "memory");
      else                    asm volatile("s_waitcnt vmcnt(3)" ::: "memory");
    } else if (T == NT_PROJ - 2) {
      asm volatile("s_waitcnt vmcnt(0)" ::: "memory");
    }
    __builtin_amdgcn_s_barrier();
  }
#undef STAGE_A
#undef STAGE_B
#undef ARD
#undef BRD

#pragma unroll
  for (int i = 0; i < FR; ++i) {
    int rbase = m0 + wm + i * 16 + lq * 4;
#pragma unroll
    for (int j = 0; j < 4; ++j) {
      int col = n0 + wn + j * 16 + lr;
#pragma unroll
      for (int r = 0; r < 4; ++r)
        C[(size_t)(rbase + r) * ldc + col] = f2bf(acc[i][j][r]);
    }
  }
}

__global__ __launch_bounds__(512, 2) void proj256(
    const unsigned short* __restrict__ Ebf,
    const unsigned short* __restrict__ WtQK,
    const unsigned short* __restrict__ WtV,
    unsigned short* __restrict__ QKo,
    unsigned short* __restrict__ Vt) {
  __shared__ __align__(16) unsigned short sA[32768];  // 64 KiB
  __shared__ __align__(16) unsigned short sB[32768];  // 64 KiB
  int x = blockIdx.x;
  if (x < 256) {
    // QK = Ebf x WtQK^T : [8192][2048], 256x256 tiles, 8-phase core
    proj8ph(Ebf, WtQK, QKo, 2 * DIM, (x >> 3) * 256, (x & 7) * 256, sA, sB);
  } else {
    // Vt = WtV x Ebf^T : [1024][8192], 128x256 tiles (half-work round), R2 core
    x -= 256;
    proj_core<128>(WtV, Ebf, Vt, BSZ * SEQ, (x >> 5) * 128, (x & 31) * 256, sA, sB);
  }
}

// ---------------- scores / PV (R6 core + R7 grid tweaks, integer tri decode) ----------------
template <typename OutT, int MODE>
__global__ __launch_bounds__(256) void gemm_nt(
    const unsigned short* __restrict__ A, int lda, long long strideA,
    const unsigned short* __restrict__ B, int ldb, long long strideB,
    OutT* __restrict__ C, int ldc, long long strideC,
    int Kdim, float scale, float* __restrict__ rowsum) {
  int m0, n0;
  if constexpr (MODE == 1) {
    int t = blockIdx.x;
    int mt = 0;
    while (((mt + 1) * (mt + 2)) / 2 <= t) mt++;
    int nt = t - (mt * (mt + 1)) / 2;
    m0 = mt * 128; n0 = nt * 128;
  } else {
    m0 = (gridDim.y - 1 - blockIdx.y) * 128;
    n0 = blockIdx.x * 128;
  }
  int Keff = (MODE == 2) ? min(Kdim, m0 + 128) : Kdim;
  A += (long long)blockIdx.z * strideA;
  B += (long long)blockIdx.z * strideB;
  C += (long long)blockIdx.z * strideC;
  rowsum += (size_t)blockIdx.z * SEQ;

  __shared__ __align__(16) unsigned short As[128][72];
  __shared__ __align__(16) unsigned short Bs[128][72];

  int tid = threadIdx.x;
  int lane = tid & 63;
  int wid = tid >> 6;
  int wm = (wid >> 1) * 64, wn = (wid & 1) * 64;
  int lr = lane & 15, lq = lane >> 4;
  int row = tid >> 3;
  int kc = (tid & 7) * 8;

  const unsigned short* Ab = A + (size_t)(m0 + row) * lda + kc;
  const unsigned short* Bb = B + (size_t)(n0 + row) * ldb + kc;
  size_t la = (size_t)32 * lda, lb = (size_t)32 * ldb;

  uint4 ra0 = *(const uint4*)(Ab);
  uint4 ra1 = *(const uint4*)(Ab + la);
  uint4 ra2 = *(const uint4*)(Ab + 2 * la);
  uint4 ra3 = *(const uint4*)(Ab + 3 * la);
  uint4 rb0 = *(const uint4*)(Bb);
  uint4 rb1 = *(const uint4*)(Bb + lb);
  uint4 rb2 = *(const uint4*)(Bb + 2 * lb);
  uint4 rb3 = *(const uint4*)(Bb + 3 * lb);

  floatx4 acc[4][4] = {};

  for (int k0 = 0; k0 < Keff; k0 += 64) {
    __syncthreads();
    *(uint4*)&As[row][kc]      = ra0;
    *(uint4*)&As[row + 32][kc] = ra1;
    *(uint4*)&As[row + 64][kc] = ra2;
    *(uint4*)&As[row + 96][kc] = ra3;
    *(uint4*)&Bs[row][kc]      = rb0;
    *(uint4*)&Bs[row + 32][kc] = rb1;
    *(uint4*)&Bs[row + 64][kc] = rb2;
    *(uint4*)&Bs[row + 96][kc] = rb3;
    if (k0 + 64 < Keff) {
      const unsigned short* An = Ab + k0 + 64;
      const unsigned short* Bn = Bb + k0 + 64;
      ra0 = *(const uint4*)(An);
      ra1 = *(const uint4*)(An + la);
      ra2 = *(const uint4*)(An + 2 * la);
      ra3 = *(const uint4*)(An + 3 * la);
      rb0 = *(const uint4*)(Bn);
      rb1 = *(const uint4*)(Bn + lb);
      rb2 = *(const uint4*)(Bn + 2 * lb);
      rb3 = *(const uint4*)(Bn + 3 * lb);
    }
    __syncthreads();
#pragma unroll
    for (int kk = 0; kk < 64; kk += 32) {
      bf16x8 af[4], bfr[4];
      int kl = kk + lq * 8;
#pragma unroll
      for (int i = 0; i < 4; i++) af[i] = *(const bf16x8*)&As[wm + i * 16 + lr][kl];
#pragma unroll
      for (int j = 0; j < 4; j++) bfr[j] = *(const bf16x8*)&Bs[wn + j * 16 + lr][kl];
#pragma unroll
      for (int i = 0; i < 4; i++)
#pragma unroll
        for (int j = 0; j < 4; j++)
          acc[i][j] = __builtin_amdgcn_mfma_f32_16x16x32_bf16(af[i], bfr[j], acc[i][j], 0, 0, 0);
    }
  }

  if constexpr (MODE == 1) {
#pragma unroll
    for (int i = 0; i < 4; i++) {
      int rbase = m0 + wm + i * 16 + lq * 4;
      float s0 = 0.f, s1 = 0.f, s2 = 0.f, s3 = 0.f;
#pragma unroll
      for (int j = 0; j < 4; j++) {
        int col = n0 + wn + j * 16 + lr;
        float e0 = (col <= rbase + 0) ? __expf(acc[i][j][0] * scale) : 0.0f;
        float e1 = (col <= rbase + 1) ? __expf(acc[i][j][1] * scale) : 0.0f;
        float e2 = (col <= rbase + 2) ? __expf(acc[i][j][2] * scale) : 0.0f;
        float e3 = (col <= rbase + 3) ? __expf(acc[i][j][3] * scale) : 0.0f;
        store_c(&C[(size_t)(rbase + 0) * ldc + col], e0);
        store_c(&C[(size_t)(rbase + 1) * ldc + col], e1);
        store_c(&C[(size_t)(rbase + 2) * ldc + col], e2);
        store_c(&C[(size_t)(rbase + 3) * ldc + col], e3);
        s0 += e0; s1 += e1; s2 += e2; s3 += e3;
      }
#pragma unroll
      for (int m = 1; m < 16; m <<= 1) {
        s0 += __shfl_xor(s0, m, 64);
        s1 += __shfl_xor(s1, m, 64);
        s2 += __shfl_xor(s2, m, 64);
        s3 += __shfl_xor(s3, m, 64);
      }
      if (lr == 0) {
        atomicAdd(&rowsum[rbase + 0], s0);
        atomicAdd(&rowsum[rbase + 1], s1);
        atomicAdd(&rowsum[rbase + 2], s2);
        atomicAdd(&rowsum[rbase + 3], s3);
      }
    }
  } else {
#pragma unroll
    for (int i = 0; i < 4; i++) {
      int rbase = m0 + wm + i * 16 + lq * 4;
      float i0 = 1.0f / rowsum[rbase + 0];
      float i1 = 1.0f / rowsum[rbase + 1];
      float i2 = 1.0f / rowsum[rbase + 2];
      float i3 = 1.0f / rowsum[rbase + 3];
#pragma unroll
      for (int j = 0; j < 4; j++) {
        int col = n0 + wn + j * 16 + lr;
        store_c(&C[(size_t)(rbase + 0) * ldc + col], acc[i][j][0] * i0);
        store_c(&C[(size_t)(rbase + 1) * ldc + col], acc[i][j][1] * i1);
        store_c(&C[(size_t)(rbase + 2) * ldc + col], acc[i][j][2] * i2);
        store_c(&C[(size_t)(rbase + 3) * ldc + col], acc[i][j][3] * i3);
      }
    }
  }
}

extern "C" void kernel_launch(void* const* d_in, const int* in_sizes, int n_in,
                              void* d_out, int out_size, void* d_ws, size_t ws_size,
                              hipStream_t stream) {
  const float* E  = (const float*)d_in[0];
  const float* Wq = (const float*)d_in[1];
  const float* Wk = (const float*)d_in[2];
  const float* Wv = (const float*)d_in[3];
  float* out = (float*)d_out;

  char* ws = (char*)d_ws;
  size_t off = 0;
  auto alloc = [&](size_t bytes) {
    void* p = ws + off;
    off += (bytes + 255) & ~(size_t)255;
    return p;
  };
  const size_t M_ALL = (size_t)BSZ * SEQ;
  unsigned short* Ebf  = (unsigned short*)alloc(M_ALL * DIM * 2);
  unsigned short* WtQK = (unsigned short*)alloc((size_t)2 * DIM * DIM * 2);
  unsigned short* WtV  = (unsigned short*)alloc((size_t)DIM * DIM * 2);
  unsigned short* QK   = (unsigned short*)alloc(M_ALL * 2 * DIM * 2);
  unsigned short* Vt   = (unsigned short*)alloc((size_t)DIM * M_ALL * 2);
  unsigned short* ExpS = (unsigned short*)alloc((size_t)BSZ * SEQ * SEQ * 2);
  float*          Rsum = (float*)alloc((size_t)BSZ * SEQ * 4);

  int nE = (int)(M_ALL * DIM);
  cast_e<<<dim3(nE / (256 * 4)), dim3(256), 0, stream>>>(E, Ebf, nE);
  transpose_w<<<dim3(32, 32, 3), dim3(32, 8), 0, stream>>>(Wq, Wk, Wv, WtQK, WtV);
  hipMemsetAsync(Rsum, 0, (size_t)BSZ * SEQ * 4, stream);

  // fused QK (256 blocks, 8-phase core) + Vt (256 half-work blocks, R2 core)
  proj256<<<dim3(512), dim3(512), 0, stream>>>(Ebf, WtQK, WtV, QK, Vt);

  // scores -> exp numerators (bf16) + rowsum atomics; packed triangular grid
  gemm_nt<unsigned short, 1><<<dim3(136, 1, BSZ), dim3(256), 0, stream>>>(
      QK, 2 * DIM, (long long)SEQ * 2 * DIM,
      QK + DIM, 2 * DIM, (long long)SEQ * 2 * DIM,
      ExpS, SEQ, (long long)SEQ * SEQ,
      DIM, 0.03125f /* 1/sqrt(1024) */, Rsum);

  // PV: out[q][d] = (sum_k expS[q][k] * Vt[d][k]) / rowsum[q]
  gemm_nt<float, 2><<<dim3(8, 16, BSZ), dim3(256), 0, stream>>>(
      ExpS, SEQ, (long long)SEQ * SEQ,
      Vt, (int)M_ALL, (long long)SEQ,
      out, DIM, (long long)SEQ * DIM,
      SEQ, 1.0f, Rsum);
}